// Round 1
// baseline (338.349 us; speedup 1.0000x reference)
//
#include <hip/hip_runtime.h>
#include <hip/hip_bf16.h>

#define D_DIM 768
#define B_DIM 8192
#define NCHUNK 32   // column chunks (grid.y)
#define CT 2        // col-tiles of 128 per chunk
#define BM 128
#define BN 128
#define BK 64

typedef __attribute__((ext_vector_type(8))) short short8;
typedef __attribute__((ext_vector_type(4))) float f32x4;

// ws layout (bytes)
#define WS_XB   0                               // bf16[8192*768] = 12,582,912
#define WS_SQ   12582912                        // float[8192]    = 32,768
#define WS_CAND 12615680                        // float[8192*32*8] = 8,388,608
#define WS_ACC  21004288                        // float[1]

__device__ __forceinline__ void gl_lds16(const void* g, void* lds) {
  __builtin_amdgcn_global_load_lds(
      (const __attribute__((address_space(1))) unsigned int*)g,
      (__attribute__((address_space(3))) unsigned int*)lds, 16, 0, 0);
}

// maintain v[0..5] = six smallest seen, sorted ascending (v[5] = max)
__device__ __forceinline__ void ins6(float c, float* v) {
  if (c < v[5]) {
    v[5] = c;
#pragma unroll
    for (int s = 5; s > 0; --s) {
      float lo = fminf(v[s - 1], v[s]);
      float hi = fmaxf(v[s - 1], v[s]);
      v[s - 1] = lo;
      v[s] = hi;
    }
  }
}

// kernel 1: cast fp32 -> bf16, row sum-of-squares (of bf16 values), zero loss acc
__global__ __launch_bounds__(256) void cast_sq_kernel(
    const float* __restrict__ x, unsigned short* __restrict__ xb,
    float* __restrict__ sq, float* __restrict__ acc) {
  const int row = blockIdx.x;
  const int t = threadIdx.x;
  if (row == 0 && t == 0) acc[0] = 0.0f;
  const float* xr = x + (size_t)row * D_DIM;
  unsigned short* xbr = xb + (size_t)row * D_DIM;
  float s = 0.0f;
  for (int c = t; c < D_DIM; c += 256) {
    __hip_bfloat16 h = __float2bfloat16(xr[c]);
    unsigned short u;
    __builtin_memcpy(&u, &h, 2);
    xbr[c] = u;
    float vb = __bfloat162float(h);
    s += vb * vb;
  }
#pragma unroll
  for (int off = 32; off > 0; off >>= 1) s += __shfl_down(s, off, 64);
  __shared__ float red[4];
  if ((t & 63) == 0) red[t >> 6] = s;
  __syncthreads();
  if (t == 0) sq[row] = red[0] + red[1] + red[2] + red[3];
}

// kernel 2: fused bf16 MFMA Gram-tile + distance + per-row top-6 selection
__global__ __launch_bounds__(256) void knn_gemm_kernel(
    const unsigned short* __restrict__ xb, const float* __restrict__ sq,
    float* __restrict__ cand) {
  // LDS: staging A[128][64]+B[128][64] bf16 (32KB) aliased with dist[64][132] f32 (33,792B)
  // candS (6,144B) lives above the alias region. Total 39,936B.
  __shared__ __align__(16) char smem[40960];
  unsigned short* As = (unsigned short*)smem;
  unsigned short* Bs = (unsigned short*)(smem + 16384);
  float* distS = (float*)smem;                 // [64][132], stride-132 pad: 2-way banks only
  float* candS = (float*)(smem + 33792);       // [64][24]

  const int t = threadIdx.x;
  const int lane = t & 63;
  const int w = t >> 6;
  const int wm = w >> 1, wn = w & 1;           // 2x2 wave grid, each wave 64x64
  const int quad = lane >> 4, m16 = lane & 15;

  const int rowTile = blockIdx.x;              // 0..63
  const int chunk = blockIdx.y;                // 0..31
  const int rowBase = rowTile * BM;

  // per-lane row ||x||^2 for the 16 rows this lane's C-fragments touch
  float rsq[16];
#pragma unroll
  for (int i = 0; i < 4; ++i)
#pragma unroll
    for (int r = 0; r < 4; ++r)
      rsq[i * 4 + r] = sq[rowBase + wm * 64 + i * 16 + quad * 4 + r];

  // running top-6 per tile-row, owned by thread t (t<128) for tile row t
  float run[6];
#pragma unroll
  for (int s = 0; s < 6; ++s) run[s] = 1e30f;

  for (int ct = 0; ct < CT; ++ct) {
    const int colBase = chunk * (CT * BN) + ct * BN;
    float csq[4];
#pragma unroll
    for (int j = 0; j < 4; ++j)
      csq[j] = sq[colBase + wn * 64 + j * 16 + m16];

    f32x4 acc[4][4];
    const f32x4 zero = {0.0f, 0.0f, 0.0f, 0.0f};
#pragma unroll
    for (int i = 0; i < 4; ++i)
#pragma unroll
      for (int j = 0; j < 4; ++j) acc[i][j] = zero;

    // K-loop: m97-style 2-barrier, global_load_lds width-16 staging
    for (int kt = 0; kt < D_DIM / BK; ++kt) {
      const int k0 = kt * BK;
      __syncthreads();  // prior LDS consumers (MFMA reads / epilogue scans) done
#pragma unroll
      for (int q = 0; q < 4; ++q) {
        const int e = q * 2048 + t * 8;        // bf16 element index in [128][64] tile
        const int r = e >> 6, c = e & 63;
        gl_lds16(xb + (size_t)(rowBase + r) * D_DIM + k0 + c, (char*)As + (size_t)e * 2);
        gl_lds16(xb + (size_t)(colBase + r) * D_DIM + k0 + c, (char*)Bs + (size_t)e * 2);
      }
      __syncthreads();  // drains vmcnt before LDS use
#pragma unroll
      for (int kk = 0; kk < 2; ++kk) {
        short8 a[4], b[4];
#pragma unroll
        for (int i = 0; i < 4; ++i)
          a[i] = *(const short8*)(As + (wm * 64 + i * 16 + m16) * 64 + kk * 32 + quad * 8);
#pragma unroll
        for (int j = 0; j < 4; ++j)
          b[j] = *(const short8*)(Bs + (wn * 64 + j * 16 + m16) * 64 + kk * 32 + quad * 8);
#pragma unroll
        for (int i = 0; i < 4; ++i)
#pragma unroll
          for (int j = 0; j < 4; ++j)
            acc[i][j] = __builtin_amdgcn_mfma_f32_16x16x32_bf16(a[i], b[j], acc[i][j], 0, 0, 0);
      }
    }

    // epilogue: distances + top-6, in two 64-row halves (dist LDS aliases A/B staging)
    for (int h = 0; h < 2; ++h) {
      __syncthreads();
      if (wm == h) {
        // C layout: col = lane&15, row = quad*4 + reg   [verified m89/m91]
#pragma unroll
        for (int i = 0; i < 4; ++i)
#pragma unroll
          for (int j = 0; j < 4; ++j)
#pragma unroll
            for (int r = 0; r < 4; ++r) {
              const int row_l = i * 16 + quad * 4 + r;          // 0..63 within half
              const int col = wn * 64 + j * 16 + m16;           // 0..127
              const float d2 = rsq[i * 4 + r] + csq[j] - 2.0f * acc[i][j][r];
              distS[row_l * 132 + col] = sqrtf(fmaxf(d2, 0.0f));
            }
      }
      __syncthreads();
      {  // scan: 4 threads per row, 32 cols each, vectorized f32x4 reads
        const int row_l = t >> 2, seg = t & 3;
        const f32x4* dr4 = (const f32x4*)(distS + row_l * 132 + seg * 32);
        float v[6];
#pragma unroll
        for (int s = 0; s < 6; ++s) v[s] = 1e30f;
#pragma unroll
        for (int c4 = 0; c4 < 8; ++c4) {
          f32x4 dv = dr4[c4];
          ins6(dv[0], v); ins6(dv[1], v); ins6(dv[2], v); ins6(dv[3], v);
        }
#pragma unroll
        for (int s = 0; s < 6; ++s) candS[row_l * 24 + seg * 6 + s] = v[s];
      }
      __syncthreads();
      if ((t >> 6) == h) {  // owner threads [h*64, h*64+64) merge their row
        const int row_l = t - h * 64;
#pragma unroll
        for (int c = 0; c < 24; ++c) ins6(candS[row_l * 24 + c], run);
      }
    }
  }

  if (t < BM) {
    float* o = cand + ((size_t)(rowBase + t) * NCHUNK + chunk) * 8;
#pragma unroll
    for (int s = 0; s < 6; ++s) o[s] = run[s];
  }
}

// kernel 3: per-row merge of chunk candidates -> log term -> global sum
__global__ __launch_bounds__(256) void knn_merge_kernel(
    const float* __restrict__ cand, float* __restrict__ acc) {
  const int r = blockIdx.x * 256 + threadIdx.x;
  const float* cr = cand + (size_t)r * (NCHUNK * 8);
  float v[6];
#pragma unroll
  for (int s = 0; s < 6; ++s) v[s] = 1e30f;
  for (int c = 0; c < NCHUNK; ++c) {
#pragma unroll
    for (int s = 0; s < 6; ++s) ins6(cr[c * 8 + s], v);
  }
  // v sorted ascending: v[0] = self (~0); knn_mean = mean(v[1..5])
  const float mean = (v[1] + v[2] + v[3] + v[4] + v[5]) * 0.2f;
  float term = logf(mean + 1e-8f);
#pragma unroll
  for (int off = 32; off > 0; off >>= 1) term += __shfl_down(term, off, 64);
  __shared__ float red[4];
  if ((threadIdx.x & 63) == 0) red[threadIdx.x >> 6] = term;
  __syncthreads();
  if (threadIdx.x == 0) atomicAdd(acc, red[0] + red[1] + red[2] + red[3]);
}

__global__ void finalize_kernel(const float* __restrict__ acc, float* __restrict__ out) {
  out[0] = -acc[0] * (1.0f / 8192.0f);
}

extern "C" void kernel_launch(void* const* d_in, const int* in_sizes, int n_in,
                              void* d_out, int out_size, void* d_ws, size_t ws_size,
                              hipStream_t stream) {
  const float* x = (const float*)d_in[0];
  float* out = (float*)d_out;
  char* ws = (char*)d_ws;
  unsigned short* xb = (unsigned short*)(ws + WS_XB);
  float* sq = (float*)(ws + WS_SQ);
  float* cand = (float*)(ws + WS_CAND);
  float* acc = (float*)(ws + WS_ACC);

  cast_sq_kernel<<<B_DIM, 256, 0, stream>>>(x, xb, sq, acc);
  knn_gemm_kernel<<<dim3(B_DIM / BM, NCHUNK), 256, 0, stream>>>(xb, sq, cand);
  knn_merge_kernel<<<B_DIM / 256, 256, 0, stream>>>(cand, acc);
  finalize_kernel<<<1, 1, 0, stream>>>(acc, out);
}

// Round 2
// 285.992 us; speedup vs baseline: 1.1831x; 1.1831x over previous
//
#include <hip/hip_runtime.h>
#include <hip/hip_bf16.h>

#define D_DIM 768
#define B_DIM 8192
#define NCHUNK 32   // column chunks (grid.y)
#define CT 2        // col-tiles of 128 per chunk
#define BM 128
#define BN 128
#define BK 64

typedef __attribute__((ext_vector_type(8))) short short8;
typedef __attribute__((ext_vector_type(4))) float f32x4;
typedef __attribute__((ext_vector_type(4))) unsigned short ushort4v;

// ws layout (bytes)
#define WS_XB   0                               // bf16[8192*768] = 12,582,912
#define WS_SQ   12582912                        // float[8192]    = 32,768
#define WS_CAND 12615680                        // float[8192*32*8] = 8,388,608
#define WS_ACC  21004288                        // float[1]

__device__ __forceinline__ void gl_lds16(const void* g, void* lds) {
  __builtin_amdgcn_global_load_lds(
      (const __attribute__((address_space(1))) unsigned int*)g,
      (__attribute__((address_space(3))) unsigned int*)lds, 16, 0, 0);
}

// maintain v[0..5] = six smallest seen, sorted ascending (v[5] = max)
__device__ __forceinline__ void ins6(float c, float* v) {
  if (c < v[5]) {
    v[5] = c;
#pragma unroll
    for (int s = 5; s > 0; --s) {
      float lo = fminf(v[s - 1], v[s]);
      float hi = fmaxf(v[s - 1], v[s]);
      v[s - 1] = lo;
      v[s] = hi;
    }
  }
}

// kernel 1: cast fp32 -> bf16 (vectorized), row sum-of-squares of bf16 values.
// one wave per row; lane reads 3 float4, writes 3 ushort4 (bf16x4).
__global__ __launch_bounds__(256) void cast_sq_kernel(
    const float* __restrict__ x, unsigned short* __restrict__ xb,
    float* __restrict__ sq, float* __restrict__ acc) {
  const int t = threadIdx.x;
  const int w = t >> 6, lane = t & 63;
  const int row = blockIdx.x * 4 + w;
  if (blockIdx.x == 0 && t == 0) acc[0] = 0.0f;
  const f32x4* xr = (const f32x4*)(x + (size_t)row * D_DIM);
  ushort4v* xbr = (ushort4v*)(xb + (size_t)row * D_DIM);
  float s = 0.0f;
#pragma unroll
  for (int c = 0; c < 3; ++c) {
    const int idx = c * 64 + lane;
    f32x4 v = xr[idx];
    ushort4v u;
#pragma unroll
    for (int e = 0; e < 4; ++e) {
      __hip_bfloat16 h = __float2bfloat16(v[e]);
      unsigned short us;
      __builtin_memcpy(&us, &h, 2);
      u[e] = us;
      float vb = __bfloat162float(h);
      s += vb * vb;
    }
    xbr[idx] = u;
  }
#pragma unroll
  for (int off = 32; off > 0; off >>= 1) s += __shfl_down(s, off, 64);
  if (lane == 0) sq[row] = s;
}

// kernel 2: fused bf16 MFMA Gram-tile + d^2 + per-row top-6 selection.
// LDS staging uses XOR swizzle: LDS slot (row r, seg s) holds global seg s^(r&7),
// so fragment ds_read_b128s spread across all 32 banks (2-way = free).
__global__ __launch_bounds__(256) void knn_gemm_kernel(
    const unsigned short* __restrict__ xb, const float* __restrict__ sq,
    float* __restrict__ cand) {
  __shared__ __align__(16) char smem[40960];
  unsigned short* As = (unsigned short*)smem;
  unsigned short* Bs = (unsigned short*)(smem + 16384);
  float* distS = (float*)smem;                 // [64][132] f32, aliases A/B staging
  float* candS = (float*)(smem + 33792);       // [64][24]

  const int t = threadIdx.x;
  const int lane = t & 63;
  const int w = t >> 6;
  const int wm = w >> 1, wn = w & 1;           // 2x2 wave grid, each wave 64x64
  const int quad = lane >> 4, m16 = lane & 15;

  const int rowTile = blockIdx.x;              // 0..63
  const int chunk = blockIdx.y;                // 0..31
  const int rowBase = rowTile * BM;

  // staging swizzle source offsets (constant across kt)
  int srcOffA[4], ldsOffA[4], srcOffB[4];
#pragma unroll
  for (int q = 0; q < 4; ++q) {
    const int e = q * 2048 + t * 8;            // bf16 element index in [128][64] tile
    const int r = e >> 6;
    const int seg = (e >> 3) & 7;
    const int sseg = seg ^ (r & 7);
    srcOffA[q] = r * D_DIM + sseg * 8;         // element offset within (rowBase, k0)
    srcOffB[q] = srcOffA[q];                   // same mapping for B
    ldsOffA[q] = e * 2;                        // byte offset (linear, lane-contiguous)
  }

  float rsq[16];
#pragma unroll
  for (int i = 0; i < 4; ++i)
#pragma unroll
    for (int r = 0; r < 4; ++r)
      rsq[i * 4 + r] = sq[rowBase + wm * 64 + i * 16 + quad * 4 + r];

  float run[6];
#pragma unroll
  for (int s = 0; s < 6; ++s) run[s] = 1e30f;

  for (int ct = 0; ct < CT; ++ct) {
    const int colBase = chunk * (CT * BN) + ct * BN;
    float csq[4];
#pragma unroll
    for (int j = 0; j < 4; ++j)
      csq[j] = sq[colBase + wn * 64 + j * 16 + m16];

    f32x4 acc[4][4];
    const f32x4 zero = {0.0f, 0.0f, 0.0f, 0.0f};
#pragma unroll
    for (int i = 0; i < 4; ++i)
#pragma unroll
      for (int j = 0; j < 4; ++j) acc[i][j] = zero;

    for (int kt = 0; kt < D_DIM / BK; ++kt) {
      const int k0 = kt * BK;
      __syncthreads();
#pragma unroll
      for (int q = 0; q < 4; ++q) {
        gl_lds16(xb + (size_t)rowBase * D_DIM + k0 + srcOffA[q], (char*)As + ldsOffA[q]);
        gl_lds16(xb + (size_t)colBase * D_DIM + k0 + srcOffB[q], (char*)Bs + ldsOffA[q]);
      }
      __syncthreads();
#pragma unroll
      for (int kk = 0; kk < 2; ++kk) {
        short8 a[4], b[4];
#pragma unroll
        for (int i = 0; i < 4; ++i) {
          const int R = wm * 64 + i * 16 + m16;
          const int s = (kk * 4 + quad) ^ (R & 7);
          a[i] = *(const short8*)(As + R * 64 + s * 8);
        }
#pragma unroll
        for (int j = 0; j < 4; ++j) {
          const int R = wn * 64 + j * 16 + m16;
          const int s = (kk * 4 + quad) ^ (R & 7);
          b[j] = *(const short8*)(Bs + R * 64 + s * 8);
        }
#pragma unroll
        for (int i = 0; i < 4; ++i)
#pragma unroll
          for (int j = 0; j < 4; ++j)
            acc[i][j] = __builtin_amdgcn_mfma_f32_16x16x32_bf16(a[i], b[j], acc[i][j], 0, 0, 0);
      }
    }

    // epilogue: d^2 (no sqrt — monotone) + top-6, two 64-row halves
    for (int h = 0; h < 2; ++h) {
      __syncthreads();
      if (wm == h) {
        // C layout: col = lane&15, row = quad*4 + reg   [verified m89/m91]
#pragma unroll
        for (int i = 0; i < 4; ++i)
#pragma unroll
          for (int j = 0; j < 4; ++j)
#pragma unroll
            for (int r = 0; r < 4; ++r) {
              const int row_l = i * 16 + quad * 4 + r;
              const int col = wn * 64 + j * 16 + m16;
              const float d2 = rsq[i * 4 + r] + csq[j] - 2.0f * acc[i][j][r];
              distS[row_l * 132 + col] = fmaxf(d2, 0.0f);
            }
      }
      __syncthreads();
      {  // 4 threads per row, 32 cols each
        const int row_l = t >> 2, seg = t & 3;
        const f32x4* dr4 = (const f32x4*)(distS + row_l * 132 + seg * 32);
        float v[6];
#pragma unroll
        for (int s = 0; s < 6; ++s) v[s] = 1e30f;
#pragma unroll
        for (int c4 = 0; c4 < 8; ++c4) {
          f32x4 dv = dr4[c4];
          ins6(dv[0], v); ins6(dv[1], v); ins6(dv[2], v); ins6(dv[3], v);
        }
#pragma unroll
        for (int s = 0; s < 6; ++s) candS[row_l * 24 + seg * 6 + s] = v[s];
      }
      __syncthreads();
      if ((t >> 6) == h) {
        const int row_l = t - h * 64;
#pragma unroll
        for (int c = 0; c < 24; ++c) ins6(candS[row_l * 24 + c], run);
      }
    }
  }

  if (t < BM) {
    float* o = cand + ((size_t)(rowBase + t) * NCHUNK + chunk) * 8;
#pragma unroll
    for (int s = 0; s < 6; ++s) o[s] = run[s];
  }
}

// kernel 3: per-row merge of chunk candidates (d^2) -> sqrt -> log -> global sum
__global__ __launch_bounds__(256) void knn_merge_kernel(
    const float* __restrict__ cand, float* __restrict__ acc) {
  const int r = blockIdx.x * 256 + threadIdx.x;
  const float* cr = cand + (size_t)r * (NCHUNK * 8);
  float v[6];
#pragma unroll
  for (int s = 0; s < 6; ++s) v[s] = 1e30f;
  for (int c = 0; c < NCHUNK; ++c) {
#pragma unroll
    for (int s = 0; s < 6; ++s) ins6(cr[c * 8 + s], v);
  }
  // v sorted ascending on d^2: v[0] = self (~0); knn_mean = mean of sqrt(v[1..5])
  const float mean =
      (sqrtf(v[1]) + sqrtf(v[2]) + sqrtf(v[3]) + sqrtf(v[4]) + sqrtf(v[5])) * 0.2f;
  float term = logf(mean + 1e-8f);
#pragma unroll
  for (int off = 32; off > 0; off >>= 1) term += __shfl_down(term, off, 64);
  __shared__ float red[4];
  if ((threadIdx.x & 63) == 0) red[threadIdx.x >> 6] = term;
  __syncthreads();
  if (threadIdx.x == 0) atomicAdd(acc, red[0] + red[1] + red[2] + red[3]);
}

__global__ void finalize_kernel(const float* __restrict__ acc, float* __restrict__ out) {
  out[0] = -acc[0] * (1.0f / 8192.0f);
}

extern "C" void kernel_launch(void* const* d_in, const int* in_sizes, int n_in,
                              void* d_out, int out_size, void* d_ws, size_t ws_size,
                              hipStream_t stream) {
  const float* x = (const float*)d_in[0];
  float* out = (float*)d_out;
  char* ws = (char*)d_ws;
  unsigned short* xb = (unsigned short*)(ws + WS_XB);
  float* sq = (float*)(ws + WS_SQ);
  float* cand = (float*)(ws + WS_CAND);
  float* acc = (float*)(ws + WS_ACC);

  cast_sq_kernel<<<B_DIM / 4, 256, 0, stream>>>(x, xb, sq, acc);
  knn_gemm_kernel<<<dim3(B_DIM / BM, NCHUNK), 256, 0, stream>>>(xb, sq, cand);
  knn_merge_kernel<<<B_DIM / 256, 256, 0, stream>>>(cand, acc);
  finalize_kernel<<<1, 1, 0, stream>>>(acc, out);
}